// Round 3
// baseline (2056.270 us; speedup 1.0000x reference)
//
#include <hip/hip_runtime.h>
#include <hip/hip_bf16.h>

// GraphUpsampler: N=4096 -> M=8192 dense GCN, 3 iterations, out = sigmoid(Xu@Xu.T) f32 [8192,8192].
// R3: same barrier-free streaming aggregation as R2, but __launch_bounds__(256,2) so the
//     allocator gets 256 unified regs/wave (R2 capped at 88 and spilled ~700MB/dispatch).

#define N_NODES 4096
#define M_NODES 8192
#define DIM 128
#define SLICE_ELEMS ((size_t)M_NODES * DIM)

typedef __attribute__((ext_vector_type(4))) float f32x4;
typedef __attribute__((ext_vector_type(8))) short bf16x8;

__device__ __forceinline__ unsigned short f2bf(float f) {
  union { float f; unsigned u; } v; v.f = f;
  unsigned r = v.u + 0x7fffu + ((v.u >> 16) & 1u);   // round-to-nearest-even
  return (unsigned short)(r >> 16);
}
__device__ __forceinline__ float bf2f(unsigned short b) {
  union { unsigned u; float f; } v; v.u = ((unsigned)b) << 16;
  return v.f;
}

__device__ __forceinline__ void gld16(unsigned short* lds, const unsigned short* g) {
  __builtin_amdgcn_global_load_lds(
      (const __attribute__((address_space(1))) unsigned int*)g,
      (__attribute__((address_space(3))) unsigned int*)lds, 16, 0, 0);
}

__device__ __forceinline__ float sigmoidf_(float x) { return 1.0f / (1.0f + __expf(-x)); }

// ---------------- small cast / init kernels ----------------

__global__ void cast_x_kernel(const float* __restrict__ X, unsigned short* __restrict__ Xu,
                              unsigned short* __restrict__ XT) {
  int idx = blockIdx.x * 256 + threadIdx.x;          // over N*DIM
  int i = idx >> 7, c = idx & 127;
  unsigned short b = f2bf(X[idx]);
  Xu[idx] = b;
  XT[(size_t)c * N_NODES + i] = b;                   // X^T [128][4096]
}

__global__ void cast_wup_kernel(const float4* __restrict__ W, ushort4* __restrict__ Wb) {
  int idx = blockIdx.x * 256 + threadIdx.x;          // over N*N/4
  float4 v = W[idx];
  ushort4 o;
  o.x = f2bf(v.x); o.y = f2bf(v.y); o.z = f2bf(v.z); o.w = f2bf(v.w);
  Wb[idx] = o;
}

__global__ void cast_wt_kernel(const float* __restrict__ W, unsigned short* __restrict__ WT) {
  int idx = blockIdx.x * 256 + threadIdx.x;          // 128*128
  int k = idx >> 7, c = idx & 127;
  WT[c * DIM + k] = f2bf(W[idx]);                    // W^T [out c][in k]
}

// A f32 -> bf16 (once) + colsum(A)
__global__ void cast_a_kernel(const float* __restrict__ A, unsigned short* __restrict__ Ab,
                              float* __restrict__ colsumA) {
  int c = blockIdx.x * 256 + threadIdx.x;
  int r0 = blockIdx.y * 128;
  float s = 0.f;
  for (int r = 0; r < 128; ++r) {
    float a = A[(size_t)(r0 + r) * N_NODES + c];
    Ab[(size_t)(r0 + r) * N_NODES + c] = f2bf(a);
    s += a;
  }
  atomicAdd(&colsumA[c], s);
}

__global__ void init_deg_kernel(const float* __restrict__ colsumA, float* __restrict__ deg) {
  int i = blockIdx.x * 256 + threadIdx.x;            // 8192
  deg[i] = (i < N_NODES) ? 2.0f * colsumA[i] : colsumA[i - N_NODES];
}

__global__ void dinv_kernel(const float* __restrict__ deg, float* __restrict__ dinv) {
  int i = blockIdx.x * 256 + threadIdx.x;
  float d = deg[i];
  dinv[i] = d > 0.f ? rsqrtf(d) : 0.f;
}

// ZsumT[c][j] = ZT[c][j] + ZT[c][4096+j]
__global__ void zsum_kernel(const unsigned short* __restrict__ ZT,
                            unsigned short* __restrict__ ZsumT) {
  int idx = blockIdx.x * 256 + threadIdx.x;          // 128*4096
  int c = idx >> 12, j = idx & 4095;
  float v = bf2f(ZT[(size_t)c * M_NODES + j]) + bf2f(ZT[(size_t)c * M_NODES + N_NODES + j]);
  ZsumT[idx] = f2bf(v);
}

// ---------------- barrier-free streaming split-K GEMM ----------------
// C_slice = A[128-rows m0..][kbase..kbase+32*kIters] @ B  (B given transposed: BT[128 n][ldb k])
// A-frags and B-frags load direct global->VGPR; no LDS, no __syncthreads.
// __launch_bounds__(256,2): 256 unified regs/wave -> frags (~96) + acc (64) fit, no spill.

__global__ __launch_bounds__(256, 2)
void agg_kernel(const unsigned short* __restrict__ A, long lda,
                const unsigned short* __restrict__ BT, long ldb,
                float* __restrict__ accBase, int sliceOff, long rowOff, int kIters) {
  const int t = threadIdx.x, w = t >> 6, lane = t & 63;
  const int q = lane >> 4, l15 = lane & 15;
  const long m0 = (long)blockIdx.x * 128;
  const long kbase = (long)blockIdx.y * 32L * kIters;

  f32x4 acc[2][8];
#pragma unroll
  for (int a = 0; a < 2; ++a)
#pragma unroll
    for (int b = 0; b < 8; ++b) acc[a][b] = (f32x4)0.f;

  const size_t ar0 = (size_t)(m0 + w * 32 + l15) * lda + kbase + q * 8;
  const size_t ar1 = ar0 + (size_t)16 * lda;
  const size_t bbase = kbase + q * 8;

  bf16x8 a0[2], a1[2], bf[2][8];

#define LOADG(KT, S)                                                              \
  do {                                                                            \
    const size_t kk_ = (size_t)(KT) * 32;                                         \
    a0[S] = *(const bf16x8*)&A[ar0 + kk_];                                        \
    a1[S] = *(const bf16x8*)&A[ar1 + kk_];                                        \
    _Pragma("unroll")                                                             \
    for (int nt = 0; nt < 8; ++nt)                                                \
      bf[S][nt] = *(const bf16x8*)&BT[(size_t)(nt * 16 + l15) * ldb + bbase + kk_];\
  } while (0)

  LOADG(0, 0);
#pragma unroll 2
  for (int kt = 0; kt < kIters; ++kt) {
    const int cur = kt & 1, nxt = cur ^ 1;
    if (kt + 1 < kIters) LOADG(kt + 1, nxt);
#pragma unroll
    for (int nt = 0; nt < 8; ++nt) {
      acc[0][nt] = __builtin_amdgcn_mfma_f32_16x16x32_bf16(a0[cur], bf[cur][nt], acc[0][nt], 0, 0, 0);
      acc[1][nt] = __builtin_amdgcn_mfma_f32_16x16x32_bf16(a1[cur], bf[cur][nt], acc[1][nt], 0, 0, 0);
    }
  }
#undef LOADG

  float* C = accBase + (size_t)(sliceOff + blockIdx.y) * SLICE_ELEMS + (size_t)(rowOff + m0) * DIM;
#pragma unroll
  for (int mt = 0; mt < 2; ++mt)
#pragma unroll
    for (int nt = 0; nt < 8; ++nt)
#pragma unroll
      for (int i = 0; i < 4; ++i)
        C[(size_t)(w * 32 + mt * 16 + q * 4 + i) * DIM + nt * 16 + l15] = acc[mt][nt][i];
}

// sum split partials + epilogue -> bf16
// mode 0: v = s + bias_row[row]
// mode 1: v = relu(dinv[row]*s + bias_col[c])
// rows < rowSplit sum nLo slices, else nHi slices.
__global__ void reduce_acc_kernel(const float* __restrict__ acc,
                                  unsigned short* __restrict__ dst,
                                  const float* __restrict__ bias_row,
                                  const float* __restrict__ bias_col,
                                  const float* __restrict__ dinv, int mode,
                                  int nLo, int nHi, int rowSplit) {
  int idx = blockIdx.x * 256 + threadIdx.x;
  int row = idx >> 7, c = idx & 127;
  int ns = (row < rowSplit) ? nLo : nHi;
  float s = 0.f;
  for (int sp = 0; sp < ns; ++sp) s += acc[(size_t)sp * SLICE_ELEMS + idx];
  float v;
  if (mode == 0) v = s + bias_row[row];
  else { v = dinv[row] * s + bias_col[c]; v = fmaxf(v, 0.f); }
  dst[idx] = f2bf(v);
}

// ---------------- rebuild: out = sigmoid(XA @ XB^T), K=128 ----------------
// MODE 0: bf16 out + fused column sums into deg.  MODE 1: f32 out (final).

template <int MODE>
__global__ __launch_bounds__(256)
void rebuild_kernel(const unsigned short* __restrict__ XA,
                    const unsigned short* __restrict__ XB,
                    void* __restrict__ out, long ldo, float* __restrict__ deg) {
  __shared__ __align__(16) unsigned short smem[32768];   // lA[4][128][32] + lB[4][128][32]
  __shared__ float lcol[128];
  unsigned short* lA = smem;
  unsigned short* lB = smem + 16384;
  const int t = threadIdx.x, w = t >> 6, lane = t & 63;
  const int q = lane >> 4, l15 = lane & 15;
  const int i0 = blockIdx.x * 128, j0 = blockIdx.y * 128;
  const int srow = t >> 2, schk = t & 3;
#pragma unroll
  for (int kk = 0; kk < 4; ++kk)
#pragma unroll
    for (int h = 0; h < 2; ++h) {
      gld16(&lA[kk * 4096 + h * 2048 + t * 8],
            &XA[(size_t)(i0 + h * 64 + srow) * DIM + kk * 32 + schk * 8]);
      gld16(&lB[kk * 4096 + h * 2048 + t * 8],
            &XB[(size_t)(j0 + h * 64 + srow) * DIM + kk * 32 + schk * 8]);
    }
  if (MODE == 0 && t < 128) lcol[t] = 0.f;
  __syncthreads();

  f32x4 acc[2][8];
#pragma unroll
  for (int a = 0; a < 2; ++a)
#pragma unroll
    for (int b = 0; b < 8; ++b) acc[a][b] = (f32x4)0.f;

#pragma unroll
  for (int kk = 0; kk < 4; ++kk) {
    bf16x8 a0 = *(const bf16x8*)&lA[kk * 4096 + (w * 32 + l15) * 32 + q * 8];
    bf16x8 a1 = *(const bf16x8*)&lA[kk * 4096 + (w * 32 + 16 + l15) * 32 + q * 8];
#pragma unroll
    for (int nt = 0; nt < 8; ++nt) {
      bf16x8 b = *(const bf16x8*)&lB[kk * 4096 + (nt * 16 + l15) * 32 + q * 8];
      acc[0][nt] = __builtin_amdgcn_mfma_f32_16x16x32_bf16(a0, b, acc[0][nt], 0, 0, 0);
      acc[1][nt] = __builtin_amdgcn_mfma_f32_16x16x32_bf16(a1, b, acc[1][nt], 0, 0, 0);
    }
  }
  __syncthreads();   // staging reads done; smem reusable as C-tile

  if (MODE == 0) {
    unsigned short* lC = smem;   // [128][136] bf16
#pragma unroll
    for (int mt = 0; mt < 2; ++mt)
#pragma unroll
      for (int nt = 0; nt < 8; ++nt) {
        float cs = 0.f;
#pragma unroll
        for (int i = 0; i < 4; ++i) {
          float sv = sigmoidf_(acc[mt][nt][i]);
          cs += sv;
          lC[(w * 32 + mt * 16 + q * 4 + i) * 136 + nt * 16 + l15] = f2bf(sv);
        }
        cs += __shfl_xor(cs, 16);
        cs += __shfl_xor(cs, 32);
        if (lane < 16) atomicAdd(&lcol[nt * 16 + lane], cs);
      }
    __syncthreads();
    unsigned short* og = (unsigned short*)out;
#pragma unroll
    for (int cc = 0; cc < 8; ++cc) {
      int ch = t + cc * 256;                     // 0..2047
      int row = ch >> 4, c16 = ch & 15;
      *(bf16x8*)&og[(size_t)(i0 + row) * ldo + j0 + c16 * 8] =
          *(const bf16x8*)&lC[row * 136 + c16 * 8];
    }
    if (t < 128) atomicAdd(&deg[j0 + t], lcol[t]);
  } else {
    float* og = (float*)out;
#pragma unroll
    for (int mt = 0; mt < 2; ++mt)
#pragma unroll
      for (int nt = 0; nt < 8; ++nt)
#pragma unroll
        for (int i = 0; i < 4; ++i)
          og[(size_t)(i0 + w * 32 + mt * 16 + q * 4 + i) * ldo + j0 + nt * 16 + l15] =
              sigmoidf_(acc[mt][nt][i]);
  }
}

// ---------------- Z^T = (dinv ⊙ (Xu @ W)) transposed, [128][8192] ----------------

__global__ __launch_bounds__(256)
void yz_kernel(const unsigned short* __restrict__ Xu, const unsigned short* __restrict__ WT,
               const float* __restrict__ dinv, unsigned short* __restrict__ ZT, int ldz) {
  __shared__ __align__(16) unsigned short smem[32768];
  unsigned short* lA = smem;
  unsigned short* lB = smem + 16384;
  const int t = threadIdx.x, w = t >> 6, lane = t & 63;
  const int q = lane >> 4, l15 = lane & 15;
  const int r0 = blockIdx.x * 128;
  const int srow = t >> 2, schk = t & 3;
#pragma unroll
  for (int kk = 0; kk < 4; ++kk)
#pragma unroll
    for (int h = 0; h < 2; ++h) {
      gld16(&lA[kk * 4096 + h * 2048 + t * 8],
            &Xu[(size_t)(r0 + h * 64 + srow) * DIM + kk * 32 + schk * 8]);
      gld16(&lB[kk * 4096 + h * 2048 + t * 8],
            &WT[(size_t)(h * 64 + srow) * DIM + kk * 32 + schk * 8]);
    }
  __syncthreads();

  f32x4 acc[2][8];
#pragma unroll
  for (int a = 0; a < 2; ++a)
#pragma unroll
    for (int b = 0; b < 8; ++b) acc[a][b] = (f32x4)0.f;

#pragma unroll
  for (int kk = 0; kk < 4; ++kk) {
    bf16x8 a0 = *(const bf16x8*)&lA[kk * 4096 + (w * 32 + l15) * 32 + q * 8];
    bf16x8 a1 = *(const bf16x8*)&lA[kk * 4096 + (w * 32 + 16 + l15) * 32 + q * 8];
#pragma unroll
    for (int nt = 0; nt < 8; ++nt) {
      bf16x8 b = *(const bf16x8*)&lB[kk * 4096 + (nt * 16 + l15) * 32 + q * 8];
      acc[0][nt] = __builtin_amdgcn_mfma_f32_16x16x32_bf16(a0, b, acc[0][nt], 0, 0, 0);
      acc[1][nt] = __builtin_amdgcn_mfma_f32_16x16x32_bf16(a1, b, acc[1][nt], 0, 0, 0);
    }
  }
  __syncthreads();
  unsigned short* lT = smem;   // transposed tile [c 128][r 136]
#pragma unroll
  for (int mt = 0; mt < 2; ++mt)
#pragma unroll
    for (int nt = 0; nt < 8; ++nt)
#pragma unroll
      for (int i = 0; i < 4; ++i) {
        int r = w * 32 + mt * 16 + q * 4 + i;
        lT[(nt * 16 + l15) * 136 + r] = f2bf(dinv[r0 + r] * acc[mt][nt][i]);
      }
  __syncthreads();
#pragma unroll
  for (int cc = 0; cc < 8; ++cc) {
    int ch = t + cc * 256;
    int c = ch >> 4, c16 = ch & 15;
    *(bf16x8*)&ZT[(size_t)c * ldz + r0 + c16 * 8] = *(const bf16x8*)&lT[c * 136 + c16 * 8];
  }
}

// ---------------- driver ----------------

extern "C" void kernel_launch(void* const* d_in, const int* in_sizes, int n_in,
                              void* d_out, int out_size, void* d_ws, size_t ws_size,
                              hipStream_t stream) {
  (void)in_sizes; (void)n_in; (void)out_size;
  const float* X   = (const float*)d_in[0];
  const float* A   = (const float*)d_in[1];
  const float* Wup = (const float*)d_in[2];
  const float* bup = (const float*)d_in[3];
  const float* W1  = (const float*)d_in[4];
  const float* b1  = (const float*)d_in[5];
  const float* W2  = (const float*)d_in[6];
  const float* b2  = (const float*)d_in[7];

  const size_t ADJ_BYTES = (size_t)M_NODES * M_NODES * 2;
  char* ws = (char*)d_ws;
  size_t off = 0;
  auto alloc = [&](size_t bytes) {
    char* p = ws + off;
    off += (bytes + 255) & ~(size_t)255;
    return p;
  };
  float*          accb    = (float*)alloc(16 * SLICE_ELEMS * 4);                 // 67 MB
  unsigned short* Xu      = (unsigned short*)alloc((size_t)M_NODES * DIM * 2);
  unsigned short* ZT      = (unsigned short*)alloc((size_t)DIM * M_NODES * 2);
  unsigned short* XT      = (unsigned short*)alloc((size_t)DIM * N_NODES * 2);
  unsigned short* ZsumT   = (unsigned short*)alloc((size_t)DIM * N_NODES * 2);
  unsigned short* W1T     = (unsigned short*)alloc(DIM * DIM * 2);
  unsigned short* W2T     = (unsigned short*)alloc(DIM * DIM * 2);
  float*          colsumA = (float*)alloc(N_NODES * 4);
  float*          deg     = (float*)alloc(M_NODES * 4);
  float*          dinv    = (float*)alloc(M_NODES * 4);
  unsigned short* Abf     = (unsigned short*)alloc((size_t)N_NODES * N_NODES * 2);  // 33.5 MB
  unsigned short* S0      = (unsigned short*)alloc((size_t)N_NODES * N_NODES * 2);  // 33.5 MB

  unsigned short* Adj;
  if (ws_size >= off + ADJ_BYTES) Adj = (unsigned short*)(ws + off);
  else                            Adj = (unsigned short*)d_out;  // Adj dead before final write
  unsigned short* Wupb = Adj;   // W_up bf16 aliases Adj (consumed before Adj first written)

  unsigned short* XuNew = Xu + (size_t)N_NODES * DIM;

  hipMemsetAsync(colsumA, 0, N_NODES * 4, stream);
  cast_x_kernel<<<N_NODES * DIM / 256, 256, 0, stream>>>(X, Xu, XT);
  cast_wup_kernel<<<((size_t)N_NODES * N_NODES / 4) / 256, 256, 0, stream>>>(
      (const float4*)Wup, (ushort4*)Wupb);
  cast_wt_kernel<<<64, 256, 0, stream>>>(W1, W1T);
  cast_wt_kernel<<<64, 256, 0, stream>>>(W2, W2T);

  // new = W_up @ X (+ b_up per-row): K=4096, 8 splits x 512
  agg_kernel<<<dim3(N_NODES / 128, 8), 256, 0, stream>>>(
      Wupb, N_NODES, XT, N_NODES, accb, 0, 0, 16);
  reduce_acc_kernel<<<N_NODES * DIM / 256, 256, 0, stream>>>(
      accb, XuNew, bup, nullptr, nullptr, 0, 8, 8, N_NODES);

  // A -> bf16 + colsum; deg; S0 = sigmoid(new@new^T) + colsum fused
  cast_a_kernel<<<dim3(N_NODES / 256, N_NODES / 128), 256, 0, stream>>>(A, Abf, colsumA);
  init_deg_kernel<<<M_NODES / 256, 256, 0, stream>>>(colsumA, deg);
  rebuild_kernel<0><<<dim3(N_NODES / 128, N_NODES / 128), 256, 0, stream>>>(
      XuNew, XuNew, S0, N_NODES, deg + N_NODES);
  dinv_kernel<<<M_NODES / 256, 256, 0, stream>>>(deg, dinv);

  // ---- iter 0, conv1 via block structure ----
  yz_kernel<<<M_NODES / 128, 256, 0, stream>>>(Xu, W1T, dinv, ZT, M_NODES);
  zsum_kernel<<<DIM * N_NODES / 256, 256, 0, stream>>>(ZT, ZsumT);
  // C_top = A @ (Zt+Zb)        -> slices 0..7, rows 0..4095
  agg_kernel<<<dim3(N_NODES / 128, 8), 256, 0, stream>>>(
      Abf, N_NODES, ZsumT, N_NODES, accb, 0, 0, 16);
  // C_bot = A @ Zt             -> slices 0..7, rows 4096..8191
  agg_kernel<<<dim3(N_NODES / 128, 8), 256, 0, stream>>>(
      Abf, N_NODES, ZT, M_NODES, accb, 0, N_NODES, 16);
  // C_bot += S0 @ Zb           -> slices 8..15, rows 4096..8191
  agg_kernel<<<dim3(N_NODES / 128, 8), 256, 0, stream>>>(
      S0, N_NODES, ZT + N_NODES, M_NODES, accb, 8, N_NODES, 16);
  reduce_acc_kernel<<<M_NODES * DIM / 256, 256, 0, stream>>>(
      accb, Xu, nullptr, b1, dinv, 1, 8, 16, N_NODES);

  for (int it = 0; it < 3; ++it) {
    if (it > 0) {
      // conv1 on full Adj (carried from previous iteration's mid-loop rebuild)
      yz_kernel<<<M_NODES / 128, 256, 0, stream>>>(Xu, W1T, dinv, ZT, M_NODES);
      agg_kernel<<<dim3(M_NODES / 128, 8), 256, 0, stream>>>(
          Adj, M_NODES, ZT, M_NODES, accb, 0, 0, 32);
      reduce_acc_kernel<<<M_NODES * DIM / 256, 256, 0, stream>>>(
          accb, Xu, nullptr, b1, dinv, 1, 8, 8, 0);
    }
    // mid-loop Adj rebuild + deg
    hipMemsetAsync(deg, 0, M_NODES * 4, stream);
    rebuild_kernel<0><<<dim3(M_NODES / 128, M_NODES / 128), 256, 0, stream>>>(
        Xu, Xu, Adj, M_NODES, deg);
    dinv_kernel<<<M_NODES / 256, 256, 0, stream>>>(deg, dinv);
    // conv2
    yz_kernel<<<M_NODES / 128, 256, 0, stream>>>(Xu, W2T, dinv, ZT, M_NODES);
    agg_kernel<<<dim3(M_NODES / 128, 8), 256, 0, stream>>>(
        Adj, M_NODES, ZT, M_NODES, accb, 0, 0, 32);
    reduce_acc_kernel<<<M_NODES * DIM / 256, 256, 0, stream>>>(
        accb, Xu, nullptr, b2, dinv, 1, 8, 8, 0);
    if (it == 2)
      rebuild_kernel<1><<<dim3(M_NODES / 128, M_NODES / 128), 256, 0, stream>>>(
          Xu, Xu, d_out, M_NODES, nullptr);
  }
}

// Round 4
// 1257.019 us; speedup vs baseline: 1.6358x; 1.6358x over previous
//
#include <hip/hip_runtime.h>
#include <hip/hip_bf16.h>

// GraphUpsampler: N=4096 -> M=8192 dense GCN, 3 iterations, out = sigmoid(Xu@Xu.T) f32 [8192,8192].
// R4: R2's streaming aggregation, but with LITERAL-indexed ping-pong fragment buffers so SROA
//     promotes them to VGPRs. (R2/R3 used runtime-indexed arrays -> alloca stayed in scratch ->
//     ~700MB/dispatch of spill traffic, VGPR_Count=88 regardless of launch_bounds.)

#define N_NODES 4096
#define M_NODES 8192
#define DIM 128
#define SLICE_ELEMS ((size_t)M_NODES * DIM)

typedef __attribute__((ext_vector_type(4))) float f32x4;
typedef __attribute__((ext_vector_type(8))) short bf16x8;

__device__ __forceinline__ unsigned short f2bf(float f) {
  union { float f; unsigned u; } v; v.f = f;
  unsigned r = v.u + 0x7fffu + ((v.u >> 16) & 1u);   // round-to-nearest-even
  return (unsigned short)(r >> 16);
}
__device__ __forceinline__ float bf2f(unsigned short b) {
  union { unsigned u; float f; } v; v.u = ((unsigned)b) << 16;
  return v.f;
}

__device__ __forceinline__ void gld16(unsigned short* lds, const unsigned short* g) {
  __builtin_amdgcn_global_load_lds(
      (const __attribute__((address_space(1))) unsigned int*)g,
      (__attribute__((address_space(3))) unsigned int*)lds, 16, 0, 0);
}

__device__ __forceinline__ float sigmoidf_(float x) { return 1.0f / (1.0f + __expf(-x)); }

// ---------------- small cast / init kernels ----------------

__global__ void cast_x_kernel(const float* __restrict__ X, unsigned short* __restrict__ Xu,
                              unsigned short* __restrict__ XT) {
  int idx = blockIdx.x * 256 + threadIdx.x;          // over N*DIM
  int i = idx >> 7, c = idx & 127;
  unsigned short b = f2bf(X[idx]);
  Xu[idx] = b;
  XT[(size_t)c * N_NODES + i] = b;                   // X^T [128][4096]
}

__global__ void cast_wup_kernel(const float4* __restrict__ W, ushort4* __restrict__ Wb) {
  int idx = blockIdx.x * 256 + threadIdx.x;          // over N*N/4
  float4 v = W[idx];
  ushort4 o;
  o.x = f2bf(v.x); o.y = f2bf(v.y); o.z = f2bf(v.z); o.w = f2bf(v.w);
  Wb[idx] = o;
}

__global__ void cast_wt_kernel(const float* __restrict__ W, unsigned short* __restrict__ WT) {
  int idx = blockIdx.x * 256 + threadIdx.x;          // 128*128
  int k = idx >> 7, c = idx & 127;
  WT[c * DIM + k] = f2bf(W[idx]);                    // W^T [out c][in k]
}

// A f32 -> bf16 (once) + colsum(A)
__global__ void cast_a_kernel(const float* __restrict__ A, unsigned short* __restrict__ Ab,
                              float* __restrict__ colsumA) {
  int c = blockIdx.x * 256 + threadIdx.x;
  int r0 = blockIdx.y * 128;
  float s = 0.f;
  for (int r = 0; r < 128; ++r) {
    float a = A[(size_t)(r0 + r) * N_NODES + c];
    Ab[(size_t)(r0 + r) * N_NODES + c] = f2bf(a);
    s += a;
  }
  atomicAdd(&colsumA[c], s);
}

__global__ void init_deg_kernel(const float* __restrict__ colsumA, float* __restrict__ deg) {
  int i = blockIdx.x * 256 + threadIdx.x;            // 8192
  deg[i] = (i < N_NODES) ? 2.0f * colsumA[i] : colsumA[i - N_NODES];
}

__global__ void dinv_kernel(const float* __restrict__ deg, float* __restrict__ dinv) {
  int i = blockIdx.x * 256 + threadIdx.x;
  float d = deg[i];
  dinv[i] = d > 0.f ? rsqrtf(d) : 0.f;
}

// ZsumT[c][j] = ZT[c][j] + ZT[c][4096+j]
__global__ void zsum_kernel(const unsigned short* __restrict__ ZT,
                            unsigned short* __restrict__ ZsumT) {
  int idx = blockIdx.x * 256 + threadIdx.x;          // 128*4096
  int c = idx >> 12, j = idx & 4095;
  float v = bf2f(ZT[(size_t)c * M_NODES + j]) + bf2f(ZT[(size_t)c * M_NODES + N_NODES + j]);
  ZsumT[idx] = f2bf(v);
}

// ---------------- barrier-free streaming split-K GEMM ----------------
// C_slice = A[128-rows m0..][kbase..+32*kIters] @ B (given BT[128 n][ldb k]).
// Direct global->VGPR fragments, explicit ping-pong with LITERAL buffer indices
// (SROA-promotable), no LDS, no barriers.

__global__ __launch_bounds__(256, 2)
void agg_kernel(const unsigned short* __restrict__ A, long lda,
                const unsigned short* __restrict__ BT, long ldb,
                float* __restrict__ accBase, int sliceOff, long rowOff, int kIters) {
  const int t = threadIdx.x, w = t >> 6, lane = t & 63;
  const int q = lane >> 4, l15 = lane & 15;
  const long m0 = (long)blockIdx.x * 128;
  const long kbase = (long)blockIdx.y * 32L * kIters;

  f32x4 acc[2][8];
#pragma unroll
  for (int a = 0; a < 2; ++a)
#pragma unroll
    for (int b = 0; b < 8; ++b) acc[a][b] = (f32x4)0.f;

  const size_t ar0 = (size_t)(m0 + w * 32 + l15) * lda + kbase + q * 8;
  const size_t ar1 = ar0 + (size_t)16 * lda;
  const size_t bbase = kbase + q * 8;

  bf16x8 a0_0, a1_0, b_0[8];   // buffer 0
  bf16x8 a0_1, a1_1, b_1[8];   // buffer 1

#define LOADG(KT, S)                                                               \
  do {                                                                             \
    const size_t kk_ = (size_t)(KT) * 32;                                          \
    a0_##S = *(const bf16x8*)&A[ar0 + kk_];                                        \
    a1_##S = *(const bf16x8*)&A[ar1 + kk_];                                        \
    _Pragma("unroll")                                                              \
    for (int nt = 0; nt < 8; ++nt)                                                 \
      b_##S[nt] = *(const bf16x8*)&BT[(size_t)(nt * 16 + l15) * ldb + bbase + kk_];\
  } while (0)

#define COMPUTE(S)                                                                  \
  do {                                                                              \
    _Pragma("unroll")                                                               \
    for (int nt = 0; nt < 8; ++nt) {                                                \
      acc[0][nt] = __builtin_amdgcn_mfma_f32_16x16x32_bf16(a0_##S, b_##S[nt], acc[0][nt], 0, 0, 0); \
      acc[1][nt] = __builtin_amdgcn_mfma_f32_16x16x32_bf16(a1_##S, b_##S[nt], acc[1][nt], 0, 0, 0); \
    }                                                                               \
  } while (0)

  LOADG(0, 0);
  int kt = 0;
#pragma unroll 1
  for (; kt + 2 < kIters; kt += 2) {
    LOADG(kt + 1, 1);
    COMPUTE(0);
    LOADG(kt + 2, 0);
    COMPUTE(1);
  }
  // tail: kt, kt+1 (kIters even, >= 2)
  LOADG(kt + 1, 1);
  COMPUTE(0);
  COMPUTE(1);
#undef LOADG
#undef COMPUTE

  float* C = accBase + (size_t)(sliceOff + blockIdx.y) * SLICE_ELEMS + (size_t)(rowOff + m0) * DIM;
#pragma unroll
  for (int mt = 0; mt < 2; ++mt)
#pragma unroll
    for (int nt = 0; nt < 8; ++nt)
#pragma unroll
      for (int i = 0; i < 4; ++i)
        C[(size_t)(w * 32 + mt * 16 + q * 4 + i) * DIM + nt * 16 + l15] = acc[mt][nt][i];
}

// sum split partials + epilogue -> bf16
// mode 0: v = s + bias_row[row]
// mode 1: v = relu(dinv[row]*s + bias_col[c])
// rows < rowSplit sum nLo slices, else nHi slices.
__global__ void reduce_acc_kernel(const float* __restrict__ acc,
                                  unsigned short* __restrict__ dst,
                                  const float* __restrict__ bias_row,
                                  const float* __restrict__ bias_col,
                                  const float* __restrict__ dinv, int mode,
                                  int nLo, int nHi, int rowSplit) {
  int idx = blockIdx.x * 256 + threadIdx.x;
  int row = idx >> 7, c = idx & 127;
  int ns = (row < rowSplit) ? nLo : nHi;
  float s = 0.f;
  for (int sp = 0; sp < ns; ++sp) s += acc[(size_t)sp * SLICE_ELEMS + idx];
  float v;
  if (mode == 0) v = s + bias_row[row];
  else { v = dinv[row] * s + bias_col[c]; v = fmaxf(v, 0.f); }
  dst[idx] = f2bf(v);
}

// ---------------- rebuild: out = sigmoid(XA @ XB^T), K=128 ----------------
// MODE 0: bf16 out + fused column sums into deg.  MODE 1: f32 out (final).

template <int MODE>
__global__ __launch_bounds__(256)
void rebuild_kernel(const unsigned short* __restrict__ XA,
                    const unsigned short* __restrict__ XB,
                    void* __restrict__ out, long ldo, float* __restrict__ deg) {
  __shared__ __align__(16) unsigned short smem[32768];   // lA[4][128][32] + lB[4][128][32]
  __shared__ float lcol[128];
  unsigned short* lA = smem;
  unsigned short* lB = smem + 16384;
  const int t = threadIdx.x, w = t >> 6, lane = t & 63;
  const int q = lane >> 4, l15 = lane & 15;
  const int i0 = blockIdx.x * 128, j0 = blockIdx.y * 128;
  const int srow = t >> 2, schk = t & 3;
#pragma unroll
  for (int kk = 0; kk < 4; ++kk)
#pragma unroll
    for (int h = 0; h < 2; ++h) {
      gld16(&lA[kk * 4096 + h * 2048 + t * 8],
            &XA[(size_t)(i0 + h * 64 + srow) * DIM + kk * 32 + schk * 8]);
      gld16(&lB[kk * 4096 + h * 2048 + t * 8],
            &XB[(size_t)(j0 + h * 64 + srow) * DIM + kk * 32 + schk * 8]);
    }
  if (MODE == 0 && t < 128) lcol[t] = 0.f;
  __syncthreads();

  f32x4 acc[2][8];
#pragma unroll
  for (int a = 0; a < 2; ++a)
#pragma unroll
    for (int b = 0; b < 8; ++b) acc[a][b] = (f32x4)0.f;

#pragma unroll
  for (int kk = 0; kk < 4; ++kk) {
    bf16x8 a0 = *(const bf16x8*)&lA[kk * 4096 + (w * 32 + l15) * 32 + q * 8];
    bf16x8 a1 = *(const bf16x8*)&lA[kk * 4096 + (w * 32 + 16 + l15) * 32 + q * 8];
#pragma unroll
    for (int nt = 0; nt < 8; ++nt) {
      bf16x8 b = *(const bf16x8*)&lB[kk * 4096 + (nt * 16 + l15) * 32 + q * 8];
      acc[0][nt] = __builtin_amdgcn_mfma_f32_16x16x32_bf16(a0, b, acc[0][nt], 0, 0, 0);
      acc[1][nt] = __builtin_amdgcn_mfma_f32_16x16x32_bf16(a1, b, acc[1][nt], 0, 0, 0);
    }
  }
  __syncthreads();   // staging reads done; smem reusable as C-tile

  if (MODE == 0) {
    unsigned short* lC = smem;   // [128][136] bf16
#pragma unroll
    for (int mt = 0; mt < 2; ++mt)
#pragma unroll
      for (int nt = 0; nt < 8; ++nt) {
        float cs = 0.f;
#pragma unroll
        for (int i = 0; i < 4; ++i) {
          float sv = sigmoidf_(acc[mt][nt][i]);
          cs += sv;
          lC[(w * 32 + mt * 16 + q * 4 + i) * 136 + nt * 16 + l15] = f2bf(sv);
        }
        cs += __shfl_xor(cs, 16);
        cs += __shfl_xor(cs, 32);
        if (lane < 16) atomicAdd(&lcol[nt * 16 + lane], cs);
      }
    __syncthreads();
    unsigned short* og = (unsigned short*)out;
#pragma unroll
    for (int cc = 0; cc < 8; ++cc) {
      int ch = t + cc * 256;                     // 0..2047
      int row = ch >> 4, c16 = ch & 15;
      *(bf16x8*)&og[(size_t)(i0 + row) * ldo + j0 + c16 * 8] =
          *(const bf16x8*)&lC[row * 136 + c16 * 8];
    }
    if (t < 128) atomicAdd(&deg[j0 + t], lcol[t]);
  } else {
    float* og = (float*)out;
#pragma unroll
    for (int mt = 0; mt < 2; ++mt)
#pragma unroll
      for (int nt = 0; nt < 8; ++nt)
#pragma unroll
        for (int i = 0; i < 4; ++i)
          og[(size_t)(i0 + w * 32 + mt * 16 + q * 4 + i) * ldo + j0 + nt * 16 + l15] =
              sigmoidf_(acc[mt][nt][i]);
  }
}

// ---------------- Z^T = (dinv ⊙ (Xu @ W)) transposed, [128][8192] ----------------

__global__ __launch_bounds__(256)
void yz_kernel(const unsigned short* __restrict__ Xu, const unsigned short* __restrict__ WT,
               const float* __restrict__ dinv, unsigned short* __restrict__ ZT, int ldz) {
  __shared__ __align__(16) unsigned short smem[32768];
  unsigned short* lA = smem;
  unsigned short* lB = smem + 16384;
  const int t = threadIdx.x, w = t >> 6, lane = t & 63;
  const int q = lane >> 4, l15 = lane & 15;
  const int r0 = blockIdx.x * 128;
  const int srow = t >> 2, schk = t & 3;
#pragma unroll
  for (int kk = 0; kk < 4; ++kk)
#pragma unroll
    for (int h = 0; h < 2; ++h) {
      gld16(&lA[kk * 4096 + h * 2048 + t * 8],
            &Xu[(size_t)(r0 + h * 64 + srow) * DIM + kk * 32 + schk * 8]);
      gld16(&lB[kk * 4096 + h * 2048 + t * 8],
            &WT[(size_t)(h * 64 + srow) * DIM + kk * 32 + schk * 8]);
    }
  __syncthreads();

  f32x4 acc[2][8];
#pragma unroll
  for (int a = 0; a < 2; ++a)
#pragma unroll
    for (int b = 0; b < 8; ++b) acc[a][b] = (f32x4)0.f;

#pragma unroll
  for (int kk = 0; kk < 4; ++kk) {
    bf16x8 a0 = *(const bf16x8*)&lA[kk * 4096 + (w * 32 + l15) * 32 + q * 8];
    bf16x8 a1 = *(const bf16x8*)&lA[kk * 4096 + (w * 32 + 16 + l15) * 32 + q * 8];
#pragma unroll
    for (int nt = 0; nt < 8; ++nt) {
      bf16x8 b = *(const bf16x8*)&lB[kk * 4096 + (nt * 16 + l15) * 32 + q * 8];
      acc[0][nt] = __builtin_amdgcn_mfma_f32_16x16x32_bf16(a0, b, acc[0][nt], 0, 0, 0);
      acc[1][nt] = __builtin_amdgcn_mfma_f32_16x16x32_bf16(a1, b, acc[1][nt], 0, 0, 0);
    }
  }
  __syncthreads();
  unsigned short* lT = smem;   // transposed tile [c 128][r 136]
#pragma unroll
  for (int mt = 0; mt < 2; ++mt)
#pragma unroll
    for (int nt = 0; nt < 8; ++nt)
#pragma unroll
      for (int i = 0; i < 4; ++i) {
        int r = w * 32 + mt * 16 + q * 4 + i;
        lT[(nt * 16 + l15) * 136 + r] = f2bf(dinv[r0 + r] * acc[mt][nt][i]);
      }
  __syncthreads();
#pragma unroll
  for (int cc = 0; cc < 8; ++cc) {
    int ch = t + cc * 256;
    int c = ch >> 4, c16 = ch & 15;
    *(bf16x8*)&ZT[(size_t)c * ldz + r0 + c16 * 8] = *(const bf16x8*)&lT[c * 136 + c16 * 8];
  }
}

// ---------------- driver ----------------

extern "C" void kernel_launch(void* const* d_in, const int* in_sizes, int n_in,
                              void* d_out, int out_size, void* d_ws, size_t ws_size,
                              hipStream_t stream) {
  (void)in_sizes; (void)n_in; (void)out_size;
  const float* X   = (const float*)d_in[0];
  const float* A   = (const float*)d_in[1];
  const float* Wup = (const float*)d_in[2];
  const float* bup = (const float*)d_in[3];
  const float* W1  = (const float*)d_in[4];
  const float* b1  = (const float*)d_in[5];
  const float* W2  = (const float*)d_in[6];
  const float* b2  = (const float*)d_in[7];

  const size_t ADJ_BYTES = (size_t)M_NODES * M_NODES * 2;
  char* ws = (char*)d_ws;
  size_t off = 0;
  auto alloc = [&](size_t bytes) {
    char* p = ws + off;
    off += (bytes + 255) & ~(size_t)255;
    return p;
  };
  float*          accb    = (float*)alloc(16 * SLICE_ELEMS * 4);                 // 67 MB
  unsigned short* Xu      = (unsigned short*)alloc((size_t)M_NODES * DIM * 2);
  unsigned short* ZT      = (unsigned short*)alloc((size_t)DIM * M_NODES * 2);
  unsigned short* XT      = (unsigned short*)alloc((size_t)DIM * N_NODES * 2);
  unsigned short* ZsumT   = (unsigned short*)alloc((size_t)DIM * N_NODES * 2);
  unsigned short* W1T     = (unsigned short*)alloc(DIM * DIM * 2);
  unsigned short* W2T     = (unsigned short*)alloc(DIM * DIM * 2);
  float*          colsumA = (float*)alloc(N_NODES * 4);
  float*          deg     = (float*)alloc(M_NODES * 4);
  float*          dinv    = (float*)alloc(M_NODES * 4);
  unsigned short* Abf     = (unsigned short*)alloc((size_t)N_NODES * N_NODES * 2);  // 33.5 MB
  unsigned short* S0      = (unsigned short*)alloc((size_t)N_NODES * N_NODES * 2);  // 33.5 MB

  unsigned short* Adj;
  if (ws_size >= off + ADJ_BYTES) Adj = (unsigned short*)(ws + off);
  else                            Adj = (unsigned short*)d_out;  // Adj dead before final write
  unsigned short* Wupb = Adj;   // W_up bf16 aliases Adj (consumed before Adj first written)

  unsigned short* XuNew = Xu + (size_t)N_NODES * DIM;

  hipMemsetAsync(colsumA, 0, N_NODES * 4, stream);
  cast_x_kernel<<<N_NODES * DIM / 256, 256, 0, stream>>>(X, Xu, XT);
  cast_wup_kernel<<<((size_t)N_NODES * N_NODES / 4) / 256, 256, 0, stream>>>(
      (const float4*)Wup, (ushort4*)Wupb);
  cast_wt_kernel<<<64, 256, 0, stream>>>(W1, W1T);
  cast_wt_kernel<<<64, 256, 0, stream>>>(W2, W2T);

  // new = W_up @ X (+ b_up per-row): K=4096, 8 splits x 512
  agg_kernel<<<dim3(N_NODES / 128, 8), 256, 0, stream>>>(
      Wupb, N_NODES, XT, N_NODES, accb, 0, 0, 16);
  reduce_acc_kernel<<<N_NODES * DIM / 256, 256, 0, stream>>>(
      accb, XuNew, bup, nullptr, nullptr, 0, 8, 8, N_NODES);

  // A -> bf16 + colsum; deg; S0 = sigmoid(new@new^T) + colsum fused
  cast_a_kernel<<<dim3(N_NODES / 256, N_NODES / 128), 256, 0, stream>>>(A, Abf, colsumA);
  init_deg_kernel<<<M_NODES / 256, 256, 0, stream>>>(colsumA, deg);
  rebuild_kernel<0><<<dim3(N_NODES / 128, N_NODES / 128), 256, 0, stream>>>(
      XuNew, XuNew, S0, N_NODES, deg + N_NODES);
  dinv_kernel<<<M_NODES / 256, 256, 0, stream>>>(deg, dinv);

  // ---- iter 0, conv1 via block structure ----
  yz_kernel<<<M_NODES / 128, 256, 0, stream>>>(Xu, W1T, dinv, ZT, M_NODES);
  zsum_kernel<<<DIM * N_NODES / 256, 256, 0, stream>>>(ZT, ZsumT);
  // C_top = A @ (Zt+Zb)        -> slices 0..7, rows 0..4095
  agg_kernel<<<dim3(N_NODES / 128, 8), 256, 0, stream>>>(
      Abf, N_NODES, ZsumT, N_NODES, accb, 0, 0, 16);
  // C_bot = A @ Zt             -> slices 0..7, rows 4096..8191
  agg_kernel<<<dim3(N_NODES / 128, 8), 256, 0, stream>>>(
      Abf, N_NODES, ZT, M_NODES, accb, 0, N_NODES, 16);
  // C_bot += S0 @ Zb           -> slices 8..15, rows 4096..8191
  agg_kernel<<<dim3(N_NODES / 128, 8), 256, 0, stream>>>(
      S0, N_NODES, ZT + N_NODES, M_NODES, accb, 8, N_NODES, 16);
  reduce_acc_kernel<<<M_NODES * DIM / 256, 256, 0, stream>>>(
      accb, Xu, nullptr, b1, dinv, 1, 8, 16, N_NODES);

  for (int it = 0; it < 3; ++it) {
    if (it > 0) {
      // conv1 on full Adj (carried from previous iteration's mid-loop rebuild)
      yz_kernel<<<M_NODES / 128, 256, 0, stream>>>(Xu, W1T, dinv, ZT, M_NODES);
      agg_kernel<<<dim3(M_NODES / 128, 8), 256, 0, stream>>>(
          Adj, M_NODES, ZT, M_NODES, accb, 0, 0, 32);
      reduce_acc_kernel<<<M_NODES * DIM / 256, 256, 0, stream>>>(
          accb, Xu, nullptr, b1, dinv, 1, 8, 8, 0);
    }
    // mid-loop Adj rebuild + deg
    hipMemsetAsync(deg, 0, M_NODES * 4, stream);
    rebuild_kernel<0><<<dim3(M_NODES / 128, M_NODES / 128), 256, 0, stream>>>(
        Xu, Xu, Adj, M_NODES, deg);
    dinv_kernel<<<M_NODES / 256, 256, 0, stream>>>(deg, dinv);
    // conv2
    yz_kernel<<<M_NODES / 128, 256, 0, stream>>>(Xu, W2T, dinv, ZT, M_NODES);
    agg_kernel<<<dim3(M_NODES / 128, 8), 256, 0, stream>>>(
        Adj, M_NODES, ZT, M_NODES, accb, 0, 0, 32);
    reduce_acc_kernel<<<M_NODES * DIM / 256, 256, 0, stream>>>(
        accb, Xu, nullptr, b2, dinv, 1, 8, 8, 0);
    if (it == 2)
      rebuild_kernel<1><<<dim3(M_NODES / 128, M_NODES / 128), 256, 0, stream>>>(
          Xu, Xu, d_out, M_NODES, nullptr);
  }
}

// Round 5
// 989.224 us; speedup vs baseline: 2.0787x; 1.2707x over previous
//
#include <hip/hip_runtime.h>
#include <hip/hip_bf16.h>

// GraphUpsampler: N=4096 -> M=8192 dense GCN, 3 iters, out = sigmoid(Xu@Xu.T) f32 [8192,8192].
// R5: Adj/Wup stored in STAGE-TILED layout so the aggregation GEMM streams HBM sequentially:
//   addr(i,k) = (tm*kcPerRow + kc)*131072 + stage*4096 + r*32 + e
//   (tm=i>>7, r=i&127, kc=k>>10, stage=(k&1023)>>5, e=k&31)
// Each agg stage = 8KB contiguous; each wave gld16 = 1KB contiguous. C-partials written in
// MFMA-native packed order (16B/lane). Final f32 rebuild repacks via LDS -> f32x4 row stores.

#define N_NODES 4096
#define M_NODES 8192
#define DIM 128
#define SLICE_ELEMS ((size_t)M_NODES * DIM)

typedef __attribute__((ext_vector_type(4))) float f32x4;
typedef __attribute__((ext_vector_type(8))) short bf16x8;

__device__ __forceinline__ unsigned short f2bf(float f) {
  union { float f; unsigned u; } v; v.f = f;
  unsigned r = v.u + 0x7fffu + ((v.u >> 16) & 1u);
  return (unsigned short)(r >> 16);
}

__device__ __forceinline__ void gld16(unsigned short* lds, const unsigned short* g) {
  __builtin_amdgcn_global_load_lds(
      (const __attribute__((address_space(1))) unsigned int*)g,
      (__attribute__((address_space(3))) unsigned int*)lds, 16, 0, 0);
}

__device__ __forceinline__ float sigmoidf_(float x) { return 1.0f / (1.0f + __expf(-x)); }

// ---------------- cast / init kernels ----------------

__global__ void cast_x_kernel(const float* __restrict__ X, unsigned short* __restrict__ Xu,
                              unsigned short* __restrict__ XT) {
  int idx = blockIdx.x * 256 + threadIdx.x;          // N*DIM
  int i = idx >> 7, c = idx & 127;
  unsigned short b = f2bf(X[idx]);
  Xu[idx] = b;
  XT[(size_t)c * N_NODES + i] = b;                   // X^T [128][4096]
}

// W_up f32 [4096][4096] -> bf16 stage-tiled (kcPerRow=4)
__global__ void cast_wup_kernel(const float4* __restrict__ W, unsigned short* __restrict__ Wb) {
  int idx4 = blockIdx.x * 256 + threadIdx.x;         // N*N/4
  int r = idx4 >> 10, c = (idx4 & 1023) << 2;
  float4 v = W[idx4];
  ushort4 o;
  o.x = f2bf(v.x); o.y = f2bf(v.y); o.z = f2bf(v.z); o.w = f2bf(v.w);
  int tm = r >> 7, rr = r & 127;
  int kc = c >> 10, st = (c & 1023) >> 5, e = c & 31;
  *(ushort4*)&Wb[((size_t)tm * 4 + kc) * 131072 + (size_t)st * 4096 + rr * 32 + e] = o;
}

__global__ void cast_wt_kernel(const float* __restrict__ W, unsigned short* __restrict__ WT) {
  int idx = blockIdx.x * 256 + threadIdx.x;          // 128*128
  int k = idx >> 7, c = idx & 127;
  WT[c * DIM + k] = f2bf(W[idx]);                    // W^T [out][in]
}

// A f32 -> 3 blocks of stage-tiled Adj ([[A,A],[A,.]], A symmetric) + colsum(A)
__global__ void cast_a_kernel(const float* __restrict__ A, unsigned short* __restrict__ Adj,
                              float* __restrict__ colsumA) {
  int c = blockIdx.x * 256 + threadIdx.x;            // grid.x = 16
  int r0 = blockIdx.y * 128;
  int tm = r0 >> 7;
  int kc = c >> 10, st = (c & 1023) >> 5, e = c & 31;
  size_t a1 = ((size_t)(tm)      * 8 + kc)     * 131072 + (size_t)st * 4096 + e;  // (r,c)
  size_t a2 = ((size_t)(tm)      * 8 + 4 + kc) * 131072 + (size_t)st * 4096 + e;  // (r,4096+c)
  size_t a3 = ((size_t)(tm + 32) * 8 + kc)     * 131072 + (size_t)st * 4096 + e;  // (4096+r,c)
  float s = 0.f;
  for (int r = 0; r < 128; ++r) {
    float a = A[(size_t)(r0 + r) * N_NODES + c];
    unsigned short b = f2bf(a);
    Adj[a1 + r * 32] = b; Adj[a2 + r * 32] = b; Adj[a3 + r * 32] = b;
    s += a;
  }
  atomicAdd(&colsumA[c], s);
}

__global__ void init_deg_kernel(const float* __restrict__ colsumA, float* __restrict__ deg) {
  int i = blockIdx.x * 256 + threadIdx.x;            // 8192
  deg[i] = (i < N_NODES) ? 2.0f * colsumA[i] : colsumA[i - N_NODES];
}

__global__ void dinv_kernel(const float* __restrict__ deg, float* __restrict__ dinv) {
  int i = blockIdx.x * 256 + threadIdx.x;
  float d = deg[i];
  dinv[i] = d > 0.f ? rsqrtf(d) : 0.f;
}

// ---------------- aggregation GEMM (split-K, tiled A) ----------------
// C_partial[slice] = At(tiled)[128 rows x 1024k per (bx,by)] @ B (BT[128 n][ldb k]).
// A stages are 8KB contiguous; C written in MFMA-native packed order.

__global__ __launch_bounds__(256, 2)
void agg_kernel(const unsigned short* __restrict__ At, long tileRowElems,
                const unsigned short* __restrict__ BT, long ldb,
                float* __restrict__ accBase, int kIters) {
  __shared__ __align__(16) unsigned short lA[4096];
  __shared__ __align__(16) unsigned short lB[4096];
  const int t = threadIdx.x, w = t >> 6, lane = t & 63;
  const int q = lane >> 4, l15 = lane & 15;
  const int sg0 = blockIdx.y * kIters;               // global stage index
  const size_t abase = (size_t)blockIdx.x * tileRowElems +
                       (size_t)(sg0 >> 5) * 131072 + (size_t)(sg0 & 31) * 4096;
  const size_t bk = (size_t)sg0 * 32;
  const int arow = t >> 2, achk = t & 3;

  f32x4 acc[2][8];
#pragma unroll
  for (int a = 0; a < 2; ++a)
#pragma unroll
    for (int b = 0; b < 8; ++b) acc[a][b] = (f32x4)0.f;

  for (int s = 0; s < kIters; ++s) {
    __syncthreads();
    gld16(&lA[t * 8],        &At[abase + (size_t)s * 4096 + t * 8]);
    gld16(&lA[2048 + t * 8], &At[abase + (size_t)s * 4096 + 2048 + t * 8]);
    gld16(&lB[t * 8],        &BT[(size_t)arow * ldb + bk + s * 32 + achk * 8]);
    gld16(&lB[2048 + t * 8], &BT[(size_t)(64 + arow) * ldb + bk + s * 32 + achk * 8]);
    __syncthreads();
    bf16x8 a0 = *(const bf16x8*)&lA[(w * 32 + l15) * 32 + q * 8];
    bf16x8 a1 = *(const bf16x8*)&lA[(w * 32 + 16 + l15) * 32 + q * 8];
#pragma unroll
    for (int nt = 0; nt < 8; ++nt) {
      bf16x8 b = *(const bf16x8*)&lB[(nt * 16 + l15) * 32 + q * 8];
      acc[0][nt] = __builtin_amdgcn_mfma_f32_16x16x32_bf16(a0, b, acc[0][nt], 0, 0, 0);
      acc[1][nt] = __builtin_amdgcn_mfma_f32_16x16x32_bf16(a1, b, acc[1][nt], 0, 0, 0);
    }
  }
  // packed C: tile*16384 + ((w*2+mt)*8+nt)*256 + (q*16+l15)*4 + i   -- 16B/lane coalesced
  float* ct = accBase + (size_t)blockIdx.y * SLICE_ELEMS + (size_t)blockIdx.x * 16384;
#pragma unroll
  for (int mt = 0; mt < 2; ++mt)
#pragma unroll
    for (int nt = 0; nt < 8; ++nt)
      *(f32x4*)&ct[(((w * 2 + mt) * 8 + nt) * 256) + (q * 16 + l15) * 4] = acc[mt][nt];
}

// sum packed partials + epilogue -> bf16 row-major
// mode 0: v = s + bias_row[row];  mode 1: v = relu(dinv[row]*s + bias_col[col])
__global__ void reduce_acc_kernel(const float* __restrict__ acc,
                                  unsigned short* __restrict__ dst,
                                  const float* __restrict__ bias_row,
                                  const float* __restrict__ bias_col,
                                  const float* __restrict__ dinv, int mode, int nSlices) {
  int p = blockIdx.x * 256 + threadIdx.x;
  float s = 0.f;
  for (int sp = 0; sp < nSlices; ++sp) s += acc[(size_t)sp * SLICE_ELEMS + p];
  int tile = p >> 14, r = p & 16383;
  int grp = r >> 8, r2 = r & 255;
  int nt = grp & 7, wmt = grp >> 3;
  int i = r2 & 3, ql = r2 >> 2;
  int row = tile * 128 + (wmt >> 1) * 32 + (wmt & 1) * 16 + (ql >> 4) * 4 + i;
  int col = nt * 16 + (ql & 15);
  float v = (mode == 0) ? (s + bias_row[row])
                        : fmaxf(dinv[row] * s + bias_col[col], 0.f);
  dst[(size_t)row * DIM + col] = f2bf(v);
}

// ---------------- rebuild: out = sigmoid(XA @ XB^T), K=128 ----------------
// MODE 0: bf16 stage-tiled out (kcPerRow=8) + fused col-sums into deg[col0+..].
// MODE 1: f32 row-major out (final), repacked via LDS for f32x4 row stores.

template <int MODE>
__global__ __launch_bounds__(256)
void rebuild_kernel(const unsigned short* __restrict__ XA,
                    const unsigned short* __restrict__ XB,
                    void* __restrict__ out, long p1 /*MODE0:row0, MODE1:ldo*/,
                    long col0, float* __restrict__ deg) {
  __shared__ __align__(16) unsigned short smem[32768];   // 64KB
  __shared__ float lcol[128];
  unsigned short* lA = smem;
  unsigned short* lB = smem + 16384;
  const int t = threadIdx.x, w = t >> 6, lane = t & 63;
  const int q = lane >> 4, l15 = lane & 15;
  const int i0 = blockIdx.x * 128, j0 = blockIdx.y * 128;
  const int srow = t >> 2, schk = t & 3;
#pragma unroll
  for (int kk = 0; kk < 4; ++kk)
#pragma unroll
    for (int h = 0; h < 2; ++h) {
      gld16(&lA[kk * 4096 + h * 2048 + t * 8],
            &XA[(size_t)(i0 + h * 64 + srow) * DIM + kk * 32 + schk * 8]);
      gld16(&lB[kk * 4096 + h * 2048 + t * 8],
            &XB[(size_t)(j0 + h * 64 + srow) * DIM + kk * 32 + schk * 8]);
    }
  if (MODE == 0 && t < 128) lcol[t] = 0.f;
  __syncthreads();

  f32x4 acc[2][8];
#pragma unroll
  for (int a = 0; a < 2; ++a)
#pragma unroll
    for (int b = 0; b < 8; ++b) acc[a][b] = (f32x4)0.f;

#pragma unroll
  for (int kk = 0; kk < 4; ++kk) {
    bf16x8 a0 = *(const bf16x8*)&lA[kk * 4096 + (w * 32 + l15) * 32 + q * 8];
    bf16x8 a1 = *(const bf16x8*)&lA[kk * 4096 + (w * 32 + 16 + l15) * 32 + q * 8];
#pragma unroll
    for (int nt = 0; nt < 8; ++nt) {
      bf16x8 b = *(const bf16x8*)&lB[kk * 4096 + (nt * 16 + l15) * 32 + q * 8];
      acc[0][nt] = __builtin_amdgcn_mfma_f32_16x16x32_bf16(a0, b, acc[0][nt], 0, 0, 0);
      acc[1][nt] = __builtin_amdgcn_mfma_f32_16x16x32_bf16(a1, b, acc[1][nt], 0, 0, 0);
    }
  }
  __syncthreads();   // staging reads done; smem reusable

  if (MODE == 0) {
    unsigned short* lC = smem;   // [128][136] bf16
#pragma unroll
    for (int mt = 0; mt < 2; ++mt)
#pragma unroll
      for (int nt = 0; nt < 8; ++nt) {
        float cs = 0.f;
#pragma unroll
        for (int i = 0; i < 4; ++i) {
          float sv = sigmoidf_(acc[mt][nt][i]);
          cs += sv;
          lC[(w * 32 + mt * 16 + q * 4 + i) * 136 + nt * 16 + l15] = f2bf(sv);
        }
        cs += __shfl_xor(cs, 16);
        cs += __shfl_xor(cs, 32);
        if (lane < 16) atomicAdd(&lcol[nt * 16 + lane], cs);
      }
    __syncthreads();
    // stage-tiled store: 16B chunks, 256B-contiguous per stage, 16KB block-local region
    unsigned short* og = (unsigned short*)out;
    const long rowbase = p1 + i0, colbase = col0 + j0;
    const size_t tb = ((size_t)(rowbase >> 7) * 8 + (colbase >> 10)) * 131072;
    const int stb = (int)((colbase & 1023) >> 5);
#pragma unroll
    for (int cc = 0; cc < 8; ++cc) {
      int ch = t + cc * 256;                     // 0..2047
      int row = ch >> 4, c16 = ch & 15;
      *(bf16x8*)&og[tb + (size_t)(stb + (c16 >> 2)) * 4096 + row * 32 + (c16 & 3) * 8] =
          *(const bf16x8*)&lC[row * 136 + c16 * 8];
    }
    if (t < 128) atomicAdd(&deg[colbase + t], lcol[t]);
  } else {
    float* og = (float*)out;
    float* lCf = (float*)smem;                   // [64][128] f32 = 32KB
#pragma unroll
    for (int h2 = 0; h2 < 2; ++h2) {
      __syncthreads();
      if ((w >> 1) == h2) {
#pragma unroll
        for (int mt = 0; mt < 2; ++mt)
#pragma unroll
          for (int nt = 0; nt < 8; ++nt)
#pragma unroll
            for (int i = 0; i < 4; ++i)
              lCf[((w & 1) * 32 + mt * 16 + q * 4 + i) * 128 + nt * 16 + l15] =
                  sigmoidf_(acc[mt][nt][i]);
      }
      __syncthreads();
#pragma unroll
      for (int j = 0; j < 8; ++j) {
        int ch = t + j * 256;                    // f32x4 units, 0..2047
        int r64 = ch >> 5, c4 = (ch & 31) * 4;
        *(f32x4*)&og[(size_t)(i0 + h2 * 64 + r64) * p1 + j0 + c4] =
            *(const f32x4*)&lCf[r64 * 128 + c4];
      }
    }
  }
}

// ---------------- Z^T = (dinv ⊙ (Xu @ W)) transposed, [128][8192] ----------------

__global__ __launch_bounds__(256)
void yz_kernel(const unsigned short* __restrict__ Xu, const unsigned short* __restrict__ WT,
               const float* __restrict__ dinv, unsigned short* __restrict__ ZT, int ldz) {
  __shared__ __align__(16) unsigned short smem[32768];
  unsigned short* lA = smem;
  unsigned short* lB = smem + 16384;
  const int t = threadIdx.x, w = t >> 6, lane = t & 63;
  const int q = lane >> 4, l15 = lane & 15;
  const int r0 = blockIdx.x * 128;
  const int srow = t >> 2, schk = t & 3;
#pragma unroll
  for (int kk = 0; kk < 4; ++kk)
#pragma unroll
    for (int h = 0; h < 2; ++h) {
      gld16(&lA[kk * 4096 + h * 2048 + t * 8],
            &Xu[(size_t)(r0 + h * 64 + srow) * DIM + kk * 32 + schk * 8]);
      gld16(&lB[kk * 4096 + h * 2048 + t * 8],
            &WT[(size_t)(h * 64 + srow) * DIM + kk * 32 + schk * 8]);
    }
  __syncthreads();

  f32x4 acc[2][8];
#pragma unroll
  for (int a = 0; a < 2; ++a)
#pragma unroll
    for (int b = 0; b < 8; ++b) acc[a][b] = (f32x4)0.f;

#pragma unroll
  for (int kk = 0; kk < 4; ++kk) {
    bf16x8 a0 = *(const bf16x8*)&lA[kk * 4096 + (w * 32 + l15) * 32 + q * 8];
    bf16x8 a1 = *(const bf16x8*)&lA[kk * 4096 + (w * 32 + 16 + l15) * 32 + q * 8];
#pragma unroll
    for (int nt = 0; nt < 8; ++nt) {
      bf16x8 b = *(const bf16x8*)&lB[kk * 4096 + (nt * 16 + l15) * 32 + q * 8];
      acc[0][nt] = __builtin_amdgcn_mfma_f32_16x16x32_bf16(a0, b, acc[0][nt], 0, 0, 0);
      acc[1][nt] = __builtin_amdgcn_mfma_f32_16x16x32_bf16(a1, b, acc[1][nt], 0, 0, 0);
    }
  }
  __syncthreads();
  unsigned short* lT = smem;   // [c 128][r 136]
#pragma unroll
  for (int mt = 0; mt < 2; ++mt)
#pragma unroll
    for (int nt = 0; nt < 8; ++nt)
#pragma unroll
      for (int i = 0; i < 4; ++i) {
        int r = w * 32 + mt * 16 + q * 4 + i;
        lT[(nt * 16 + l15) * 136 + r] = f2bf(dinv[r0 + r] * acc[mt][nt][i]);
      }
  __syncthreads();
#pragma unroll
  for (int cc = 0; cc < 8; ++cc) {
    int ch = t + cc * 256;
    int c = ch >> 4, c16 = ch & 15;
    *(bf16x8*)&ZT[(size_t)c * ldz + r0 + c16 * 8] = *(const bf16x8*)&lT[c * 136 + c16 * 8];
  }
}

// ---------------- driver ----------------

extern "C" void kernel_launch(void* const* d_in, const int* in_sizes, int n_in,
                              void* d_out, int out_size, void* d_ws, size_t ws_size,
                              hipStream_t stream) {
  (void)in_sizes; (void)n_in; (void)out_size;
  const float* X   = (const float*)d_in[0];
  const float* A   = (const float*)d_in[1];
  const float* Wup = (const float*)d_in[2];
  const float* bup = (const float*)d_in[3];
  const float* W1  = (const float*)d_in[4];
  const float* b1  = (const float*)d_in[5];
  const float* W2  = (const float*)d_in[6];
  const float* b2  = (const float*)d_in[7];

  const size_t ADJ_BYTES = (size_t)M_NODES * M_NODES * 2;
  char* ws = (char*)d_ws;
  size_t off = 0;
  auto alloc = [&](size_t bytes) {
    char* p = ws + off;
    off += (bytes + 255) & ~(size_t)255;
    return p;
  };
  float*          accb    = (float*)alloc(8 * SLICE_ELEMS * 4);                  // 33.5 MB
  unsigned short* Xu      = (unsigned short*)alloc((size_t)M_NODES * DIM * 2);
  unsigned short* ZT      = (unsigned short*)alloc((size_t)DIM * M_NODES * 2);
  unsigned short* XT      = (unsigned short*)alloc((size_t)DIM * N_NODES * 2);
  unsigned short* W1T     = (unsigned short*)alloc(DIM * DIM * 2);
  unsigned short* W2T     = (unsigned short*)alloc(DIM * DIM * 2);
  float*          colsumA = (float*)alloc(N_NODES * 4);
  float*          deg     = (float*)alloc(M_NODES * 4);
  float*          dinv    = (float*)alloc(M_NODES * 4);

  unsigned short* Adj;
  if (ws_size >= off + ADJ_BYTES) Adj = (unsigned short*)(ws + off);
  else                            Adj = (unsigned short*)d_out;  // Adj dead before final write
  unsigned short* Wupb = Adj;   // tiled W_up aliases Adj (consumed before Adj first written)

  unsigned short* XuNew = Xu + (size_t)N_NODES * DIM;

  hipMemsetAsync(colsumA, 0, N_NODES * 4, stream);
  cast_x_kernel<<<N_NODES * DIM / 256, 256, 0, stream>>>(X, Xu, XT);
  cast_wup_kernel<<<((size_t)N_NODES * N_NODES / 4) / 256, 256, 0, stream>>>(
      (const float4*)Wup, Wupb);
  cast_wt_kernel<<<64, 256, 0, stream>>>(W1, W1T);
  cast_wt_kernel<<<64, 256, 0, stream>>>(W2, W2T);

  // new = W_up @ X (+ b_up): K=4096 tiled (kcPerRow=4), 8 splits x kIters=16
  agg_kernel<<<dim3(N_NODES / 128, 8), 256, 0, stream>>>(
      Wupb, 4L * 131072, XT, N_NODES, accb, 16);
  reduce_acc_kernel<<<N_NODES * DIM / 256, 256, 0, stream>>>(
      accb, XuNew, bup, nullptr, nullptr, 0, 8);

  // Adj blocks [[A,A],[A,.]] tiled + colsum; deg; S = sigmoid(new@new^T) into (4096+,4096+)
  cast_a_kernel<<<dim3(N_NODES / 256, N_NODES / 128), 256, 0, stream>>>(A, Adj, colsumA);
  init_deg_kernel<<<M_NODES / 256, 256, 0, stream>>>(colsumA, deg);
  rebuild_kernel<0><<<dim3(N_NODES / 128, N_NODES / 128), 256, 0, stream>>>(
      XuNew, XuNew, Adj, N_NODES, N_NODES, deg);
  dinv_kernel<<<M_NODES / 256, 256, 0, stream>>>(deg, dinv);

  for (int it = 0; it < 3; ++it) {
    // conv1
    yz_kernel<<<M_NODES / 128, 256, 0, stream>>>(Xu, W1T, dinv, ZT, M_NODES);
    agg_kernel<<<dim3(M_NODES / 128, 8), 256, 0, stream>>>(
        Adj, 8L * 131072, ZT, M_NODES, accb, 32);
    reduce_acc_kernel<<<M_NODES * DIM / 256, 256, 0, stream>>>(
        accb, Xu, nullptr, b1, dinv, 1, 8);
    // mid-loop Adj rebuild + deg
    hipMemsetAsync(deg, 0, M_NODES * 4, stream);
    rebuild_kernel<0><<<dim3(M_NODES / 128, M_NODES / 128), 256, 0, stream>>>(
        Xu, Xu, Adj, 0, 0, deg);
    dinv_kernel<<<M_NODES / 256, 256, 0, stream>>>(deg, dinv);
    // conv2
    yz_kernel<<<M_NODES / 128, 256, 0, stream>>>(Xu, W2T, dinv, ZT, M_NODES);
    agg_kernel<<<dim3(M_NODES / 128, 8), 256, 0, stream>>>(
        Adj, 8L * 131072, ZT, M_NODES, accb, 32);
    reduce_acc_kernel<<<M_NODES * DIM / 256, 256, 0, stream>>>(
        accb, Xu, nullptr, b2, dinv, 1, 8);
    if (it == 2)
      rebuild_kernel<1><<<dim3(M_NODES / 128, M_NODES / 128), 256, 0, stream>>>(
          Xu, Xu, d_out, M_NODES, 0, nullptr);
  }
}